// Round 9
// baseline (295.411 us; speedup 1.0000x reference)
//
#include <hip/hip_runtime.h>
#include <hip/hip_bf16.h>
#include <cstdint>
#include <cstddef>

// BaseNet: B=262144 samples, d=512.
// H = relu(reshape(combined,[2B,512]) @ W_in + b_in)   [2B,128]
// m[s] = 0.5*(H[2s]+H[2s+1])                           [B,128]
// g1 = relu(m @ W1 + b1); g2 = relu(g1 @ W2 + b2)      [B,128],[B,64]
// out = sigmoid(g2 . (W_out[:64]+W_out[64:]) + b_out)  [B]
//
// Round-9: single change vs R4 (best, 279us) = M stored in kB's FRAGMENT
// layout [F][ks][lane][8] so kB's layer-2 A-loads are 1KB-contiguous wave
// reads (were 16B segments at 256B stride = R1 anti-pattern). kA writes it
// via its (enlarged, 16-sample) XOR-swizzled bounce at zero extra cost.
// R7/R8 established: kA is NOT limited by stream count, latency depth, or
// occupancy; R4's kA structure is kept verbatim.

#define NROWS   524288   // 2B
#define NSAMP   262144   // B

typedef __attribute__((ext_vector_type(8))) short  bf16x8;
typedef __attribute__((ext_vector_type(4))) float  f32x4;

#define LGKM0() asm volatile("s_waitcnt lgkmcnt(0)" ::: "memory")

__device__ __forceinline__ unsigned short f2bf(float f) {
    unsigned u = __float_as_uint(f);
    u += 0x7fffu + ((u >> 16) & 1u);   // round-to-nearest-even
    return (unsigned short)(u >> 16);
}

// packed bf16 convert: 4x v_cvt_pk_bf16_f32 (RNE, same numerics as f2bf)
__device__ __forceinline__ bf16x8 cvt8(f32x4 lo, f32x4 hi) {
    union { unsigned u[4]; bf16x8 v; } r;
    asm("v_cvt_pk_bf16_f32 %0, %1, %2" : "=v"(r.u[0]) : "v"(lo[0]), "v"(lo[1]));
    asm("v_cvt_pk_bf16_f32 %0, %1, %2" : "=v"(r.u[1]) : "v"(lo[2]), "v"(lo[3]));
    asm("v_cvt_pk_bf16_f32 %0, %1, %2" : "=v"(r.u[2]) : "v"(hi[0]), "v"(hi[1]));
    asm("v_cvt_pk_bf16_f32 %0, %1, %2" : "=v"(r.u[3]) : "v"(hi[2]), "v"(hi[3]));
    return r.v;
}

__device__ __forceinline__ f32x4 mfma16(bf16x8 a, bf16x8 b, f32x4 c) {
    return __builtin_amdgcn_mfma_f32_16x16x32_bf16(a, b, c, 0, 0, 0);
}

// ---------------- workspace layout (bytes) ----------------
#define WS_M     0                       // Mf frag-layout [16384 F][4 ks][64 l][8] bf16 = 64 MB
#define WS_WIN   67108864                // Win frags: 16*8*64*8 bf16 = 131072 B
#define WS_W1    67239936                // W1 frags:  4*8*64*8 bf16 = 32768 B
#define WS_W2    67272704                // W2 frags:  4*4*64*8 bf16 = 16384 B
#define WS_WEFF  67289088                // 64 floats

// ---------------- prep: pack weights to MFMA B-fragment layout ----------------
// Standard B-frag (16x16x32): lane l holds B[k=(l>>4)*8+j][col=l&15], j=0..7.
// fWin uses the PERMUTED k mapping matching kA's coalesced A loads:
//   slot j of lane (lg=l>>4): k = (j<4) ? lg*4+j : 16+lg*4+(j-4)  (within 32-group)
__global__ void prep_kernel(const float* __restrict__ W_in,
                            const float* __restrict__ W1,
                            const float* __restrict__ W2,
                            const float* __restrict__ W_out,
                            unsigned short* __restrict__ fWin,
                            unsigned short* __restrict__ fW1,
                            unsigned short* __restrict__ fW2,
                            float* __restrict__ weff) {
    int tid = blockIdx.x * 256 + threadIdx.x;
    if (tid < 65536) {                       // W_in [512][128]: KT=16, NT=8 (permuted k)
        int e = tid;
        int j = e & 7, l = (e >> 3) & 63, rest = e >> 9;
        int n = rest & 7, kt = rest >> 3;
        int lg = l >> 4;
        int kin = (j < 4) ? (lg * 4 + j) : (16 + lg * 4 + (j - 4));
        int k = kt * 32 + kin;
        int col = n * 16 + (l & 15);
        fWin[e] = f2bf(W_in[k * 128 + col]);
    } else if (tid < 65536 + 16384) {        // W1 [128][128]: KT=4, NT=8 (standard)
        int e = tid - 65536;
        int j = e & 7, l = (e >> 3) & 63, rest = e >> 9;
        int n = rest & 7, kt = rest >> 3;
        int k = kt * 32 + ((l >> 4) << 3) + j;
        int col = n * 16 + (l & 15);
        fW1[e] = f2bf(W1[k * 128 + col]);
    } else if (tid < 65536 + 16384 + 8192) { // W2 [128][64]: KT=4, NT=4 (standard)
        int e = tid - 65536 - 16384;
        int j = e & 7, l = (e >> 3) & 63, rest = e >> 9;
        int n = rest & 3, kt = rest >> 2;
        int k = kt * 32 + ((l >> 4) << 3) + j;
        int col = n * 16 + (l & 15);
        fW2[e] = f2bf(W2[k * 64 + col]);
    } else if (tid < 65536 + 16384 + 8192 + 64) {
        int c = tid - (65536 + 16384 + 8192);
        weff[c] = W_out[c] + W_out[64 + c];
    }
}

// ---------------- kernel A: GEMM + bias/relu + node-mean -> Mf (frag bf16) --
// R4 structure verbatim: 256 blocks x 512 thr = 8 waves (2/EU),
// waves_per_eu(2,2) pins the 256-VGPR budget (R2/R3 lesson). Grid-strided
// tiles (dense 128MB window). Permuted-k A loads: 16 rows x 64B contiguous
// per instr. Triple-buffered 64-float chunks, prefetch distance 2.
// NEW epilogue: 16-sample XOR-swizzled bounce -> per-ks readback -> Mf
// fragment layout [F][ks][64][8], 4x1KB contiguous stores per wave.
// LDS: 128K W_in + 8 waves x 4KB bounce = 160 KB exactly.
__global__ void __launch_bounds__(512) __attribute__((amdgpu_waves_per_eu(2, 2)))
kA(const float* __restrict__ A,              // [2B][512] fp32 (= combined)
   const unsigned short* __restrict__ fWin,  // frag layout (permuted k)
   const float* __restrict__ b_in,
   unsigned short* __restrict__ Mf) {        // frag-layout m
    __shared__ __align__(16) unsigned short lds[81920];  // 160 KB exactly
    unsigned short* lwin = lds;                          // 131072 B: W_in frags
    {
        const f32x4* src = (const f32x4*)fWin;
        f32x4* dst = (f32x4*)lds;
        int tid = threadIdx.x;
        #pragma unroll
        for (int i = 0; i < 16; ++i) dst[i * 512 + tid] = src[i * 512 + tid];
    }
    __syncthreads();
    const int w = threadIdx.x >> 6, l = threadIdx.x & 63;
    const int lr = l & 15, lg = l >> 4;
    char* bw = (char*)lds + 131072 + w * 4096;  // per-wave 4KB bounce (16 samp)
    float binv[8];
    #pragma unroll
    for (int n = 0; n < 8; ++n) binv[n] = b_in[n * 16 + lr];

    for (int t = blockIdx.x; t < NROWS / 256; t += 256) {
        const size_t rowbase = (size_t)t * 256 + (size_t)w * 32;  // wave: 32 rows
        const float* a0 = A + (rowbase + lr) * 512 + lg * 4;
        const float* a1 = a0 + (size_t)16 * 512;

        f32x4 acc[2][8];
        #pragma unroll
        for (int rt = 0; rt < 2; ++rt)
            #pragma unroll
            for (int n = 0; n < 8; ++n) acc[rt][n] = (f32x4){0.f, 0.f, 0.f, 0.f};

        // triple-buffered staging: [buf][rowtile][ks][half], chunk = 64 floats
        f32x4 st[3][2][2][2];
        #pragma unroll
        for (int pc = 0; pc < 2; ++pc) {
            #pragma unroll
            for (int ks = 0; ks < 2; ++ks) {
                st[pc][0][ks][0] = *(const f32x4*)(a0 + pc * 64 + ks * 32);
                st[pc][0][ks][1] = *(const f32x4*)(a0 + pc * 64 + ks * 32 + 16);
                st[pc][1][ks][0] = *(const f32x4*)(a1 + pc * 64 + ks * 32);
                st[pc][1][ks][1] = *(const f32x4*)(a1 + pc * 64 + ks * 32 + 16);
            }
        }
        #pragma unroll
        for (int c = 0; c < 8; ++c) {           // 8 chunks x 64 floats
            const int cb = c % 3;
            if (c < 6) {
                const int nb = (c + 2) % 3;
                #pragma unroll
                for (int ks = 0; ks < 2; ++ks) {
                    st[nb][0][ks][0] = *(const f32x4*)(a0 + (c + 2) * 64 + ks * 32);
                    st[nb][0][ks][1] = *(const f32x4*)(a0 + (c + 2) * 64 + ks * 32 + 16);
                    st[nb][1][ks][0] = *(const f32x4*)(a1 + (c + 2) * 64 + ks * 32);
                    st[nb][1][ks][1] = *(const f32x4*)(a1 + (c + 2) * 64 + ks * 32 + 16);
                }
            }
            #pragma unroll
            for (int ks = 0; ks < 2; ++ks) {
                const int kg = c * 2 + ks;
                bf16x8 af0 = cvt8(st[cb][0][ks][0], st[cb][0][ks][1]);
                bf16x8 af1 = cvt8(st[cb][1][ks][0], st[cb][1][ks][1]);
                #pragma unroll
                for (int n = 0; n < 8; ++n) {
                    bf16x8 bf = *(const bf16x8*)&lwin[((kg * 8 + n) * 64 + l) * 8];
                    acc[0][n] = mfma16(af0, bf, acc[0][n]);
                    acc[1][n] = mfma16(af1, bf, acc[1][n]);
                }
            }
        }
        // ---- epilogue: bias+relu+pair-mean -> 16-sample swizzled bounce ----
        // C layout: row=(l>>4)*4+r, col=l&15; rows 2s,2s+1 pair to sample s.
        // rt=0 -> local samples 0..7, rt=1 -> 8..15.
        #pragma unroll
        for (int rt = 0; rt < 2; ++rt) {
            #pragma unroll
            for (int n = 0; n < 8; ++n) {
                const float b = binv[n];
                float h0 = fmaxf(acc[rt][n][0] + b, 0.f);
                float h1 = fmaxf(acc[rt][n][1] + b, 0.f);
                float h2 = fmaxf(acc[rt][n][2] + b, 0.f);
                float h3 = fmaxf(acc[rt][n][3] + b, 0.f);
                int s0i = rt * 8 + 2 * lg, s1i = s0i + 1;
                int col2 = (n * 16 + lr) * 2;
                *(unsigned short*)(bw + s0i * 256 + (col2 ^ ((s0i & 7) << 4))) = f2bf(0.5f * (h0 + h1));
                *(unsigned short*)(bw + s1i * 256 + (col2 ^ ((s1i & 7) << 4))) = f2bf(0.5f * (h2 + h3));
            }
        }
        LGKM0();   // same-wave ds_write -> ds_read
        // readback per-ks A-fragments, store Mf [F][ks][lane][8] contiguous.
        // lane l wants m[local s=lr][lg*8 + ks*32 .. +8].
        const size_t F = (size_t)t * 8 + (size_t)w;
        #pragma unroll
        for (int ks = 0; ks < 4; ++ks) {
            int roff = lr * 256 + (((unsigned)(lg * 16 + ks * 64)) ^ ((lr & 7) << 4));
            bf16x8 v = *(const bf16x8*)(bw + roff);
            *(bf16x8*)&Mf[F * 2048 + ks * 512 + l * 8] = v;
        }
        // DS ops are wave-ordered: next tile's bounce writes can't pass these reads.
    }
}

// ---------------- kernel B: m -> g1 -> g2 -> sigmoid(score) -----------------
// 512 blocks (2/CU), 4 waves x 16 samples per tile-iter. A-frags now load
// directly from Mf (fragment layout): 4 x 1KB-contiguous wave reads.
__global__ void __launch_bounds__(256, 2)
kB(const unsigned short* __restrict__ Mf,
   const unsigned short* __restrict__ fW1,
   const unsigned short* __restrict__ fW2,
   const float* __restrict__ weff,
   const float* __restrict__ b1,
   const float* __restrict__ b2,
   const float* __restrict__ b_out,
   float* __restrict__ out) {
    __shared__ unsigned short lw1[16384];       // 32 KB
    __shared__ unsigned short lw2[8192];        // 16 KB
    __shared__ unsigned short bounce[4][2048];  // 4 waves x 4 KB
    {
        int tid = threadIdx.x;
        const f32x4* s1 = (const f32x4*)fW1;
        f32x4* d1 = (f32x4*)lw1;
        #pragma unroll
        for (int i = 0; i < 8; ++i) d1[i * 256 + tid] = s1[i * 256 + tid];
        const f32x4* s2 = (const f32x4*)fW2;
        f32x4* d2 = (f32x4*)lw2;
        #pragma unroll
        for (int i = 0; i < 4; ++i) d2[i * 256 + tid] = s2[i * 256 + tid];
    }
    __syncthreads();
    const int w = threadIdx.x >> 6, l = threadIdx.x & 63;
    const int lr = l & 15, lg = l >> 4;
    float b1v[8], b2v[4], wev[4];
    #pragma unroll
    for (int n = 0; n < 8; ++n) b1v[n] = b1[n * 16 + lr];
    #pragma unroll
    for (int n = 0; n < 4; ++n) { b2v[n] = b2[n * 16 + lr]; wev[n] = weff[n * 16 + lr]; }
    const float bo = b_out[0];

    for (int t = blockIdx.x; t < NSAMP / 64; t += 512) {
        const int s0 = t * 64 + w * 16;
        const size_t F = (size_t)t * 4 + (size_t)w;
        // ---- layer 2: g1 = relu(m @ W1 + b1); A-frags straight from Mf ----
        f32x4 acc1[8];
        #pragma unroll
        for (int n = 0; n < 8; ++n) acc1[n] = (f32x4){0.f, 0.f, 0.f, 0.f};
        #pragma unroll
        for (int ks = 0; ks < 4; ++ks) {
            bf16x8 af = *(const bf16x8*)&Mf[F * 2048 + ks * 512 + l * 8];
            #pragma unroll
            for (int n = 0; n < 8; ++n) {
                bf16x8 bf = *(const bf16x8*)&lw1[((ks * 8 + n) * 64 + l) * 8];
                acc1[n] = __builtin_amdgcn_mfma_f32_16x16x32_bf16(af, bf, acc1[n], 0, 0, 0);
            }
        }
        #pragma unroll
        for (int n = 0; n < 8; ++n) {
            #pragma unroll
            for (int rr = 0; rr < 4; ++rr) {
                float g = fmaxf(acc1[n][rr] + b1v[n], 0.f);
                int row = lg * 4 + rr, col = n * 16 + lr;
                int boff = row * 256 + ((col * 2) ^ ((row & 7) << 4));
                bounce[w][boff >> 1] = f2bf(g);
            }
        }
        f32x4 acc2[4];
        #pragma unroll
        for (int n = 0; n < 4; ++n) acc2[n] = (f32x4){0.f, 0.f, 0.f, 0.f};
        #pragma unroll
        for (int ks = 0; ks < 4; ++ks) {
            int roff = lr * 256 + ((ks * 64 + lg * 16) ^ ((lr & 7) << 4));
            bf16x8 af2 = *(const bf16x8*)((const char*)&bounce[w][0] + roff);
            #pragma unroll
            for (int n = 0; n < 4; ++n) {
                bf16x8 bf = *(const bf16x8*)&lw2[((ks * 4 + n) * 64 + l) * 8];
                acc2[n] = __builtin_amdgcn_mfma_f32_16x16x32_bf16(af2, bf, acc2[n], 0, 0, 0);
            }
        }
        float p0 = 0.f, p1 = 0.f, p2 = 0.f, p3 = 0.f;
        #pragma unroll
        for (int n = 0; n < 4; ++n) {
            p0 += fmaxf(acc2[n][0] + b2v[n], 0.f) * wev[n];
            p1 += fmaxf(acc2[n][1] + b2v[n], 0.f) * wev[n];
            p2 += fmaxf(acc2[n][2] + b2v[n], 0.f) * wev[n];
            p3 += fmaxf(acc2[n][3] + b2v[n], 0.f) * wev[n];
        }
        #pragma unroll
        for (int m = 1; m < 16; m <<= 1) {
            p0 += __shfl_xor(p0, m);
            p1 += __shfl_xor(p1, m);
            p2 += __shfl_xor(p2, m);
            p3 += __shfl_xor(p3, m);
        }
        float s0f = 1.f / (1.f + expf(-(p0 + bo)));
        float s1f = 1.f / (1.f + expf(-(p1 + bo)));
        float s2f = 1.f / (1.f + expf(-(p2 + bo)));
        float s3f = 1.f / (1.f + expf(-(p3 + bo)));
        if (lr < 4) {
            float v = (lr == 0) ? s0f : (lr == 1) ? s1f : (lr == 2) ? s2f : s3f;
            out[s0 + lg * 4 + lr] = v;
        }
    }
}

// ---------------- host launcher ----------------
extern "C" void kernel_launch(void* const* d_in, const int* in_sizes, int n_in,
                              void* d_out, int out_size, void* d_ws, size_t ws_size,
                              hipStream_t stream) {
    const float* combined = (const float*)d_in[0];
    const float* W_in  = (const float*)d_in[1];
    const float* b_in  = (const float*)d_in[2];
    const float* W1    = (const float*)d_in[3];
    const float* b1    = (const float*)d_in[4];
    const float* W2    = (const float*)d_in[5];
    const float* b2    = (const float*)d_in[6];
    const float* W_out = (const float*)d_in[7];
    const float* b_out = (const float*)d_in[8];
    float* out = (float*)d_out;

    char* ws = (char*)d_ws;
    unsigned short* Mf   = (unsigned short*)(ws + WS_M);
    unsigned short* fWin = (unsigned short*)(ws + WS_WIN);
    unsigned short* fW1  = (unsigned short*)(ws + WS_W1);
    unsigned short* fW2  = (unsigned short*)(ws + WS_W2);
    float* weff          = (float*)(ws + WS_WEFF);

    prep_kernel<<<(65536 + 16384 + 8192 + 64 + 255) / 256, 256, 0, stream>>>(
        W_in, W1, W2, W_out, fWin, fW1, fW2, weff);
    kA<<<256, 512, 0, stream>>>(combined, fWin, b_in, Mf);
    kB<<<512, 256, 0, stream>>>(Mf, fW1, fW2, weff, b1, b2, b_out, out);
}